// Round 4
// baseline (51147.842 us; speedup 1.0000x reference)
//
#include <hip/hip_runtime.h>
#include <math.h>

#define BATCH 512
#define SEQ   200
#define DIN   64
#define HID   512
#define GW    2048   // 4*HID
#define EPS   1e-5f
#define NBLOCKS 256

typedef _Float16 half_t;
typedef half_t half8 __attribute__((ext_vector_type(8)));
typedef float  f32x4 __attribute__((ext_vector_type(4)));

#define WN0 (2048*64)     // W_ih0 elems
#define WN1 (2048*512)    // W_hh0 / W_ih1 / W_hh1 elems
#define WTOT (WN0 + 3*WN1)

__device__ __forceinline__ float sigf(float x){ return 1.0f/(1.0f+expf(-x)); }

__device__ __forceinline__ void wave_red4(float&a,float&b,float&c,float&d){
  #pragma unroll
  for(int o=32;o;o>>=1){
    a+=__shfl_xor(a,o); b+=__shfl_xor(b,o);
    c+=__shfl_xor(c,o); d+=__shfl_xor(d,o);
  }
}

// Manual grid barrier: device-scope atomics (cross-XCD coherent, m20) +
// full __threadfence on both sides (write-back + invalidate through L2).
// Requires all blocks resident: 256 blocks at >=2 blocks/CU capacity on 256 CUs.
__device__ __forceinline__ void grid_barrier(int* cnt, int* gen){
  __threadfence();
  __syncthreads();
  if (threadIdx.x==0){
    int g = __hip_atomic_load(gen, __ATOMIC_RELAXED, __HIP_MEMORY_SCOPE_AGENT);
    int old = __hip_atomic_fetch_add(cnt, 1, __ATOMIC_ACQ_REL, __HIP_MEMORY_SCOPE_AGENT);
    if (old == NBLOCKS-1){
      __hip_atomic_store(cnt, 0, __ATOMIC_RELAXED, __HIP_MEMORY_SCOPE_AGENT);
      __hip_atomic_store(gen, g+1, __ATOMIC_RELEASE, __HIP_MEMORY_SCOPE_AGENT);
    } else {
      while (__hip_atomic_load(gen, __ATOMIC_ACQUIRE, __HIP_MEMORY_SCOPE_AGENT) == g){
        __builtin_amdgcn_s_sleep(8);
      }
    }
  }
  __syncthreads();
  __threadfence();
}

// ---------------- one-shot prep kernels ----------------

__global__ __launch_bounds__(256) void ln1_stats(const float* __restrict__ x,
                                                 float* __restrict__ mu,
                                                 float* __restrict__ rs){
  const int b = blockIdx.x;
  const float* xb = x + (size_t)b*SEQ*DIN;
  float s=0, ss=0;
  for (int i=threadIdx.x; i<SEQ*DIN; i+=256){ float v=xb[i]; s+=v; ss+=v*v; }
  __shared__ float red[8];
  #pragma unroll
  for(int o=32;o;o>>=1){ s+=__shfl_down(s,o); ss+=__shfl_down(ss,o); }
  const int lane = threadIdx.x & 63, wid = threadIdx.x>>6;
  if(lane==0){ red[wid*2]=s; red[wid*2+1]=ss; }
  __syncthreads();
  if (threadIdx.x==0){
    s = red[0]+red[2]+red[4]+red[6];
    ss = red[1]+red[3]+red[5]+red[7];
    float m = s*(1.0f/(SEQ*DIN));
    mu[b] = m;
    rs[b] = rsqrtf(ss*(1.0f/(SEQ*DIN)) - m*m + EPS);
  }
}

__global__ __launch_bounds__(256) void wsplit(
    const float* __restrict__ W0, const float* __restrict__ W1,
    const float* __restrict__ W2, const float* __restrict__ W3,
    half_t* __restrict__ Wh, half_t* __restrict__ Wl)
{
  int i = blockIdx.x*256 + threadIdx.x;
  if (i >= WTOT) return;
  const float* src; int off;
  if      (i < WN0)        { src=W0; off=i; }
  else if (i < WN0+WN1)    { src=W1; off=i-WN0; }
  else if (i < WN0+2*WN1)  { src=W2; off=i-WN0-WN1; }
  else                     { src=W3; off=i-WN0-2*WN1; }
  float v = src[off];
  half_t h = (half_t)v;
  Wh[i] = h;
  Wl[i] = (half_t)(v - (float)h);
}

// ---------------- persistent recurrence kernel ----------------

struct Params {
  const float *x, *g1, *b1;
  const float *mu, *rs;
  const float *b_ih0, *b_hh0, *b_ih1, *b_hh1;
  const float *g_ih0, *be_ih0, *g_hh0, *be_hh0, *g_ho0, *be_ho0;
  const float *g_ih1, *be_ih1, *g_hh1, *be_hh1, *g_ho1, *be_ho1;
  const half_t *Wh, *Wl;
  float *G;
  float *h0, *c0, *h1, *c1;
  half_t *h0h, *h0l, *h1h, *h1l;
  int *bcnt, *bgen;
};

// 256 blocks x 256 threads, regular launch + manual grid barrier (2/tick).
// Phase A: 4 gate GEMMs, split-fp16 3-product MFMA.
//   bid = mgrp*64 + which*16 + nblk  -> XCD = nblk%8 (B-slice stays L2-local)
//   block tile m=128 (2 sequential m-halves, B frags reused), n=128.
// Phase B: wave-per-(layer,row): gate LN + cell update + h LN, all-register.
__global__ __launch_bounds__(256,2) void lstm_persistent(Params P)
{
  const int bid  = blockIdx.x;
  const int tid  = threadIdx.x;
  const int lane = tid & 63;
  const int w    = tid >> 6;

  // ---- phase A mapping ----
  const int nblk  = bid & 15;
  const int which = (bid >> 4) & 3;
  const int mgrp  = bid >> 6;           // 0..3 -> m base = mgrp*128
  const int lrow  = lane & 15;          // A: m, B: n, D: col
  const int lk    = (lane >> 4) * 8;    // k offset within 32-chunk
  const int wn0   = nblk*128 + (w&1)*64;          // wave n origin (64 cols)
  const int wmb   = mgrp*128 + (w>>1)*32;         // wave m origin (+mh*64)

  const half_t *Ah = P.h0h, *Al = P.h0l, *Bh, *Bl; const float* bias; int Kd = HID;
  if      (which==0){ Bh=P.Wh;            Bl=P.Wl;            bias=P.b_ih0; Kd=DIN; }
  else if (which==1){ Bh=P.Wh+WN0;        Bl=P.Wl+WN0;        bias=P.b_hh0; }
  else if (which==2){ Bh=P.Wh+WN0+WN1;    Bl=P.Wl+WN0+WN1;    bias=P.b_ih1; }
  else { Ah=P.h1h; Al=P.h1l; Bh=P.Wh+WN0+2*WN1; Bl=P.Wl+WN0+2*WN1; bias=P.b_hh1; }
  float* Gout = P.G + (size_t)which*BATCH*GW;
  float bnv[4];
  #pragma unroll
  for (int ni=0;ni<4;ni++) bnv[ni] = bias[wn0+ni*16+lrow];

  // ---- phase B mapping: task = bid*4+w covers 2 layers x 512 rows ----
  const int task  = (bid<<2) | w;
  const int layer = (task >> 9) & 1;
  const int row   = task & 511;
  const float *Ga_,*Gb_,*gA,*bA,*gB,*bB,*gH,*bH; float *cs,*hs; half_t *hh,*hl;
  if (layer==0){
    Ga_ = P.G + (size_t)row*GW;
    Gb_ = Ga_ + (size_t)BATCH*GW;
    gA=P.g_ih0; bA=P.be_ih0; gB=P.g_hh0; bB=P.be_hh0; gH=P.g_ho0; bH=P.be_ho0;
    cs=P.c0+(size_t)row*HID; hs=P.h0+(size_t)row*HID;
    hh=P.h0h+(size_t)row*HID; hl=P.h0l+(size_t)row*HID;
  } else {
    Ga_ = P.G + 2*(size_t)BATCH*GW + (size_t)row*GW;
    Gb_ = Ga_ + (size_t)BATCH*GW;
    gA=P.g_ih1; bA=P.be_ih1; gB=P.g_hh1; bB=P.be_hh1; gH=P.g_ho1; bH=P.be_ho1;
    cs=P.c1+(size_t)row*HID; hs=P.h1+(size_t)row*HID;
    hh=P.h1h+(size_t)row*HID; hl=P.h1l+(size_t)row*HID;
  }

  for (int t = 0; t <= SEQ; ++t) {
    // ================= phase A: gate GEMMs =================
    {
      f32x4 acc[2][2][4];
      #pragma unroll
      for (int mh=0;mh<2;mh++)
        #pragma unroll
        for (int mi=0;mi<2;mi++)
          #pragma unroll
          for (int ni=0;ni<4;ni++)
            acc[mh][mi][ni] = (f32x4){0.f,0.f,0.f,0.f};

      const int tq = (t < SEQ) ? t : (SEQ-1);   // t==200 layer0 result unused

      for (int k0 = 0; k0 < Kd; k0 += 32) {
        half8 bh[4], bl[4];
        #pragma unroll
        for (int ni=0;ni<4;ni++){
          const size_t boff = (size_t)(wn0+ni*16+lrow)*Kd + k0 + lk;
          bh[ni] = *(const half8*)(Bh + boff);
          bl[ni] = *(const half8*)(Bl + boff);
        }
        #pragma unroll
        for (int mh=0;mh<2;mh++){
          half8 ah[2], al[2];
          #pragma unroll
          for (int mi=0;mi<2;mi++){
            if (which == 0) {
              const int b = wmb + mh*64 + mi*16 + lrow;
              const float m_ = P.mu[b], r_ = P.rs[b];
              const float* xp = P.x  + (size_t)b*(SEQ*DIN) + (size_t)tq*DIN + k0 + lk;
              const float* gp = P.g1 + (size_t)tq*DIN + k0 + lk;
              const float* bp = P.b1 + (size_t)tq*DIN + k0 + lk;
              #pragma unroll
              for (int j=0;j<8;j++){
                float v = (xp[j]-m_)*r_*gp[j] + bp[j];
                half_t hv = (half_t)v;
                ah[mi][j] = hv;
                al[mi][j] = (half_t)(v - (float)hv);
              }
            } else {
              const size_t aoff = (size_t)(wmb + mh*64 + mi*16 + lrow)*Kd + k0 + lk;
              ah[mi] = *(const half8*)(Ah + aoff);
              al[mi] = *(const half8*)(Al + aoff);
            }
          }
          #pragma unroll
          for (int mi=0;mi<2;mi++)
            #pragma unroll
            for (int ni=0;ni<4;ni++){
              acc[mh][mi][ni] = __builtin_amdgcn_mfma_f32_16x16x32_f16(ah[mi], bh[ni], acc[mh][mi][ni], 0,0,0);
              acc[mh][mi][ni] = __builtin_amdgcn_mfma_f32_16x16x32_f16(al[mi], bh[ni], acc[mh][mi][ni], 0,0,0);
              acc[mh][mi][ni] = __builtin_amdgcn_mfma_f32_16x16x32_f16(ah[mi], bl[ni], acc[mh][mi][ni], 0,0,0);
            }
        }
      }

      // C/D layout: col = lane&15, row = (lane>>4)*4 + r
      #pragma unroll
      for (int mh=0;mh<2;mh++){
        #pragma unroll
        for (int mi=0;mi<2;mi++){
          const int mb = wmb + mh*64 + mi*16 + (lane>>4)*4;
          #pragma unroll
          for (int ni=0;ni<4;ni++){
            const int n = wn0 + ni*16 + lrow;
            #pragma unroll
            for (int r=0;r<4;r++)
              Gout[(size_t)(mb+r)*GW + n] = acc[mh][mi][ni][r] + bnv[ni];
          }
        }
      }
    }
    grid_barrier(P.bcnt, P.bgen);

    // ================= phase B: LN + cell update =================
    {
      const bool active = (layer==0) ? (t < SEQ) : (t > 0);
      if (active) {
        float ga[32], gb[32];
        float sa=0, ssa=0, sb=0, ssb=0;
        #pragma unroll
        for (int i=0;i<32;i++){
          const int idx = ((i>>3)*512) + ((i&7)*64) + lane;  // gate=i>>3, r=i&7
          float va = Ga_[idx], vb = Gb_[idx];
          ga[i]=va; gb[i]=vb;
          sa+=va; ssa+=va*va; sb+=vb; ssb+=vb*vb;
        }
        wave_red4(sa,ssa,sb,ssb);
        const float ma = sa*(1.0f/GW);
        const float ra = rsqrtf(ssa*(1.0f/GW) - ma*ma + EPS);
        const float mb_ = sb*(1.0f/GW);
        const float rb = rsqrtf(ssb*(1.0f/GW) - mb_*mb_ + EPS);

        float u[8], so_[8];
        float su=0, suu=0, d2=0, d3=0;
        #pragma unroll
        for (int r=0;r<8;r++){
          const int j = r*64 + lane;
          float iv = ((ga[r   ]-ma)*ra*gA[j       ]+bA[j       ]) + ((gb[r   ]-mb_)*rb*gB[j       ]+bB[j       ]);
          float fv = ((ga[8+r ]-ma)*ra*gA[j+  HID ]+bA[j+  HID ]) + ((gb[8+r ]-mb_)*rb*gB[j+  HID ]+bB[j+  HID ]);
          float gv = ((ga[16+r]-ma)*ra*gA[j+2*HID ]+bA[j+2*HID ]) + ((gb[16+r]-mb_)*rb*gB[j+2*HID ]+bB[j+2*HID ]);
          float ov = ((ga[24+r]-ma)*ra*gA[j+3*HID ]+bA[j+3*HID ]) + ((gb[24+r]-mb_)*rb*gB[j+3*HID ]+bB[j+3*HID ]);
          float cn = sigf(fv)*cs[j] + sigf(iv)*tanhf(gv);
          cs[j] = cn;
          float uu = tanhf(cn);
          u[r]=uu; so_[r]=sigf(ov);
          su+=uu; suu+=uu*uu;
        }
        wave_red4(su,suu,d2,d3);
        const float mu_u = su*(1.0f/HID);
        const float ru   = rsqrtf(suu*(1.0f/HID) - mu_u*mu_u + EPS);
        #pragma unroll
        for (int r=0;r<8;r++){
          const int j = r*64 + lane;
          float v = so_[r] * ((u[r]-mu_u)*ru*gH[j] + bH[j]);
          hs[j] = v;
          half_t hv = (half_t)v;
          hh[j] = hv;
          hl[j] = (half_t)(v - (float)hv);
        }
      }
    }
    grid_barrier(P.bcnt, P.bgen);
  }
}

// ---------------- dense head ----------------
__global__ __launch_bounds__(256) void head_kernel(
    const float* __restrict__ h1,
    const float* __restrict__ Wd1, const float* __restrict__ bd1,
    const float* __restrict__ Wd2, const float* __restrict__ bd2,
    const float* __restrict__ Wd3, const float* __restrict__ bd3,
    const float* __restrict__ Wd4, const float* __restrict__ bd4,
    float* __restrict__ out)
{
  const int b = blockIdx.x;
  __shared__ float hv[HID];
  __shared__ float z1[128];
  __shared__ float z2[64];
  __shared__ float z3[32];
  const int tid = threadIdx.x;
  for (int i=tid;i<HID;i+=256) hv[i]=h1[(size_t)b*HID+i];
  __syncthreads();
  if (tid<128){
    float acc=bd1[tid]; const float* w=Wd1+(size_t)tid*512;
    for(int k=0;k<512;k++) acc+=hv[k]*w[k];
    z1[tid]=fmaxf(acc,0.f);
  }
  __syncthreads();
  if (tid<64){
    float acc=bd2[tid]; const float* w=Wd2+(size_t)tid*128;
    for(int k=0;k<128;k++) acc+=z1[k]*w[k];
    z2[tid]=fmaxf(acc,0.f);
  }
  __syncthreads();
  if (tid<32){
    float acc=bd3[tid]; const float* w=Wd3+(size_t)tid*64;
    for(int k=0;k<64;k++) acc+=z2[k]*w[k];
    z3[tid]=fmaxf(acc,0.f);
  }
  __syncthreads();
  if (tid==0){
    float acc=bd4[0];
    for(int k=0;k<32;k++) acc+=z3[k]*Wd4[k];
    out[b]=acc;
  }
}

extern "C" void kernel_launch(void* const* d_in, const int* in_sizes, int n_in,
                              void* d_out, int out_size, void* d_ws, size_t ws_size,
                              hipStream_t stream) {
  const float* x      = (const float*)d_in[0];
  const float* ln1_g  = (const float*)d_in[1];
  const float* ln1_b  = (const float*)d_in[2];
  const float* W_ih0  = (const float*)d_in[3];
  const float* b_ih0  = (const float*)d_in[4];
  const float* W_hh0  = (const float*)d_in[5];
  const float* b_hh0  = (const float*)d_in[6];
  const float* g_ih0  = (const float*)d_in[7];
  const float* be_ih0 = (const float*)d_in[8];
  const float* g_hh0  = (const float*)d_in[9];
  const float* be_hh0 = (const float*)d_in[10];
  const float* g_ho0  = (const float*)d_in[11];
  const float* be_ho0 = (const float*)d_in[12];
  const float* W_ih1  = (const float*)d_in[13];
  const float* b_ih1  = (const float*)d_in[14];
  const float* W_hh1  = (const float*)d_in[15];
  const float* b_hh1  = (const float*)d_in[16];
  const float* g_ih1  = (const float*)d_in[17];
  const float* be_ih1 = (const float*)d_in[18];
  const float* g_hh1  = (const float*)d_in[19];
  const float* be_hh1 = (const float*)d_in[20];
  const float* g_ho1  = (const float*)d_in[21];
  const float* be_ho1 = (const float*)d_in[22];
  const float* Wd1    = (const float*)d_in[23];
  const float* bd1    = (const float*)d_in[24];
  const float* Wd2    = (const float*)d_in[25];
  const float* bd2    = (const float*)d_in[26];
  const float* Wd3    = (const float*)d_in[27];
  const float* bd3    = (const float*)d_in[28];
  const float* Wd4    = (const float*)d_in[29];
  const float* bd4    = (const float*)d_in[30];
  float* out = (float*)d_out;

  // ---- workspace layout ----
  float* ws = (float*)d_ws;
  float* G  = ws;                                   // 4*512*2048 floats = 16 MB
  float* h0 = G  + 4*(size_t)BATCH*GW;              // fp32 state block (zeroed)
  float* c0 = h0 + (size_t)BATCH*HID;
  float* h1 = c0 + (size_t)BATCH*HID;
  float* c1 = h1 + (size_t)BATCH*HID;
  half_t* h0h = (half_t*)(c1 + (size_t)BATCH*HID);  // fp16 state splits (zeroed)
  half_t* h0l = h0h + (size_t)BATCH*HID;
  half_t* h1h = h0l + (size_t)BATCH*HID;
  half_t* h1l = h1h + (size_t)BATCH*HID;
  float* mu = (float*)(h1l + (size_t)BATCH*HID);    // 512
  float* rs = mu + BATCH;                           // 512
  half_t* Wh = (half_t*)(rs + BATCH);               // WTOT halves
  half_t* Wl = Wh + (size_t)WTOT;                   // WTOT halves
  int* bar = (int*)(Wl + (size_t)WTOT);             // {cnt, gen}

  hipMemsetAsync(h0, 0, 4*(size_t)BATCH*HID*4 + 4*(size_t)BATCH*HID*2, stream);
  hipMemsetAsync(bar, 0, 2*sizeof(int), stream);
  ln1_stats<<<BATCH, 256, 0, stream>>>(x, mu, rs);
  wsplit<<<(WTOT+255)/256, 256, 0, stream>>>(W_ih0, W_hh0, W_ih1, W_hh1, Wh, Wl);

  Params P;
  P.x=x; P.g1=ln1_g; P.b1=ln1_b; P.mu=mu; P.rs=rs;
  P.b_ih0=b_ih0; P.b_hh0=b_hh0; P.b_ih1=b_ih1; P.b_hh1=b_hh1;
  P.g_ih0=g_ih0; P.be_ih0=be_ih0; P.g_hh0=g_hh0; P.be_hh0=be_hh0; P.g_ho0=g_ho0; P.be_ho0=be_ho0;
  P.g_ih1=g_ih1; P.be_ih1=be_ih1; P.g_hh1=g_hh1; P.be_hh1=be_hh1; P.g_ho1=g_ho1; P.be_ho1=be_ho1;
  P.Wh=Wh; P.Wl=Wl; P.G=G;
  P.h0=h0; P.c0=c0; P.h1=h1; P.c1=c1;
  P.h0h=h0h; P.h0l=h0l; P.h1h=h1h; P.h1l=h1l;
  P.bcnt=bar; P.bgen=bar+1;

  lstm_persistent<<<NBLOCKS, 256, 0, stream>>>(P);

  head_kernel<<<BATCH, 256, 0, stream>>>(h1, Wd1, bd1, Wd2, bd2, Wd3, bd3, Wd4, bd4, out);
}

// Round 5
// 23865.057 us; speedup vs baseline: 2.1432x; 2.1432x over previous
//
#include <hip/hip_runtime.h>
#include <math.h>

#define BATCH 512
#define SEQ   200
#define DIN   64
#define HID   512
#define GW    2048   // 4*HID
#define EPS   1e-5f
#define NBLOCKS 256

typedef _Float16 half_t;
typedef half_t half8 __attribute__((ext_vector_type(8)));
typedef float  f32x4 __attribute__((ext_vector_type(4)));

#define WN0 (2048*64)     // W_ih0 elems
#define WN1 (2048*512)    // W_hh0 / W_ih1 / W_hh1 elems
#define WTOT (WN0 + 3*WN1)

__device__ __forceinline__ float sigf(float x){ return 1.0f/(1.0f+expf(-x)); }

__device__ __forceinline__ void wave_red4(float&a,float&b,float&c,float&d){
  #pragma unroll
  for(int o=32;o;o>>=1){
    a+=__shfl_xor(a,o); b+=__shfl_xor(b,o);
    c+=__shfl_xor(c,o); d+=__shfl_xor(d,o);
  }
}

// Sense-reversing grid barrier, cache-friendly version.
// KEY: spin with RELAXED loads (no per-iteration buffer_inv!), exactly one
// release fence (wbl2) before arrival and one acquire fence (inv) after the
// generation flips, executed by thread 0 only. __syncthreads() before entry
// guarantees every wave's stores have reached L2 (vmcnt(0) at the barrier);
// the release fence then flushes this XCD's L2 to the coherence point.
__device__ __forceinline__ void grid_barrier(int* cnt, int* gen){
  __syncthreads();
  if (threadIdx.x==0){
    __builtin_amdgcn_fence(__ATOMIC_RELEASE, "agent");   // wbl2: publish our writes
    int g = __hip_atomic_load(gen, __ATOMIC_RELAXED, __HIP_MEMORY_SCOPE_AGENT);
    int old = __hip_atomic_fetch_add(cnt, 1, __ATOMIC_RELAXED, __HIP_MEMORY_SCOPE_AGENT);
    if (old == NBLOCKS-1){
      __hip_atomic_store(cnt, 0, __ATOMIC_RELAXED, __HIP_MEMORY_SCOPE_AGENT);
      __hip_atomic_store(gen, g+1, __ATOMIC_RELAXED, __HIP_MEMORY_SCOPE_AGENT);
    } else {
      while (__hip_atomic_load(gen, __ATOMIC_RELAXED, __HIP_MEMORY_SCOPE_AGENT) == g){
        __builtin_amdgcn_s_sleep(1);
      }
    }
    __builtin_amdgcn_fence(__ATOMIC_ACQUIRE, "agent");   // inv L1+L2: see others' writes
  }
  __syncthreads();
}

// ---------------- one-shot prep kernels ----------------

__global__ __launch_bounds__(256) void ln1_stats(const float* __restrict__ x,
                                                 float* __restrict__ mu,
                                                 float* __restrict__ rs){
  const int b = blockIdx.x;
  const float* xb = x + (size_t)b*SEQ*DIN;
  float s=0, ss=0;
  for (int i=threadIdx.x; i<SEQ*DIN; i+=256){ float v=xb[i]; s+=v; ss+=v*v; }
  __shared__ float red[8];
  #pragma unroll
  for(int o=32;o;o>>=1){ s+=__shfl_down(s,o); ss+=__shfl_down(ss,o); }
  const int lane = threadIdx.x & 63, wid = threadIdx.x>>6;
  if(lane==0){ red[wid*2]=s; red[wid*2+1]=ss; }
  __syncthreads();
  if (threadIdx.x==0){
    s = red[0]+red[2]+red[4]+red[6];
    ss = red[1]+red[3]+red[5]+red[7];
    float m = s*(1.0f/(SEQ*DIN));
    mu[b] = m;
    rs[b] = rsqrtf(ss*(1.0f/(SEQ*DIN)) - m*m + EPS);
  }
}

__global__ __launch_bounds__(256) void wsplit(
    const float* __restrict__ W0, const float* __restrict__ W1,
    const float* __restrict__ W2, const float* __restrict__ W3,
    half_t* __restrict__ Wh, half_t* __restrict__ Wl)
{
  int i = blockIdx.x*256 + threadIdx.x;
  if (i >= WTOT) return;
  const float* src; int off;
  if      (i < WN0)        { src=W0; off=i; }
  else if (i < WN0+WN1)    { src=W1; off=i-WN0; }
  else if (i < WN0+2*WN1)  { src=W2; off=i-WN0-WN1; }
  else                     { src=W3; off=i-WN0-2*WN1; }
  float v = src[off];
  half_t h = (half_t)v;
  Wh[i] = h;
  Wl[i] = (half_t)(v - (float)h);
}

// ---------------- persistent recurrence kernel ----------------

struct Params {
  const float *x, *g1, *b1;
  const float *mu, *rs;
  const float *b_ih0, *b_hh0, *b_ih1, *b_hh1;
  const float *g_ih0, *be_ih0, *g_hh0, *be_hh0, *g_ho0, *be_ho0;
  const float *g_ih1, *be_ih1, *g_hh1, *be_hh1, *g_ho1, *be_ho1;
  const half_t *Wh, *Wl;
  float *G;
  float *h0, *c0, *h1, *c1;
  half_t *h0h, *h0l, *h1h, *h1l;
  int *bcnt, *bgen;
};

// 256 blocks x 256 threads, regular launch + manual grid barrier (2/tick).
// Phase A: 4 gate GEMMs, split-fp16 3-product MFMA.
//   bid = mgrp*64 + which*16 + nblk  -> XCD = bid%8 = f(which,nblk): the 4 mgrp
//   blocks sharing a B-slice land on one XCD (one L2 fetch per slice per tick).
//   block tile m=128 (2 sequential m-halves, B frags reused), n=128.
// Phase B: wave-per-(layer,row): gate LN + cell update + h LN, all-register.
__global__ __launch_bounds__(256,2) void lstm_persistent(Params P)
{
  const int bid  = blockIdx.x;
  const int tid  = threadIdx.x;
  const int lane = tid & 63;
  const int w    = tid >> 6;

  // ---- phase A mapping ----
  const int nblk  = bid & 15;
  const int which = (bid >> 4) & 3;
  const int mgrp  = bid >> 6;           // 0..3 -> m base = mgrp*128
  const int lrow  = lane & 15;          // A: m, B: n, D: col
  const int lk    = (lane >> 4) * 8;    // k offset within 32-chunk
  const int wn0   = nblk*128 + (w&1)*64;          // wave n origin (64 cols)
  const int wmb   = mgrp*128 + (w>>1)*32;         // wave m origin (+mh*64)

  const half_t *Ah = P.h0h, *Al = P.h0l, *Bh, *Bl; const float* bias; int Kd = HID;
  if      (which==0){ Bh=P.Wh;            Bl=P.Wl;            bias=P.b_ih0; Kd=DIN; }
  else if (which==1){ Bh=P.Wh+WN0;        Bl=P.Wl+WN0;        bias=P.b_hh0; }
  else if (which==2){ Bh=P.Wh+WN0+WN1;    Bl=P.Wl+WN0+WN1;    bias=P.b_ih1; }
  else { Ah=P.h1h; Al=P.h1l; Bh=P.Wh+WN0+2*WN1; Bl=P.Wl+WN0+2*WN1; bias=P.b_hh1; }
  float* Gout = P.G + (size_t)which*BATCH*GW;
  float bnv[4];
  #pragma unroll
  for (int ni=0;ni<4;ni++) bnv[ni] = bias[wn0+ni*16+lrow];

  // ---- phase B mapping: task = bid*4+w covers 2 layers x 512 rows ----
  const int task  = (bid<<2) | w;
  const int layer = (task >> 9) & 1;
  const int row   = task & 511;
  const float *Ga_,*Gb_,*gA,*bA,*gB,*bB,*gH,*bH; float *cs,*hs; half_t *hh,*hl;
  if (layer==0){
    Ga_ = P.G + (size_t)row*GW;
    Gb_ = Ga_ + (size_t)BATCH*GW;
    gA=P.g_ih0; bA=P.be_ih0; gB=P.g_hh0; bB=P.be_hh0; gH=P.g_ho0; bH=P.be_ho0;
    cs=P.c0+(size_t)row*HID; hs=P.h0+(size_t)row*HID;
    hh=P.h0h+(size_t)row*HID; hl=P.h0l+(size_t)row*HID;
  } else {
    Ga_ = P.G + 2*(size_t)BATCH*GW + (size_t)row*GW;
    Gb_ = Ga_ + (size_t)BATCH*GW;
    gA=P.g_ih1; bA=P.be_ih1; gB=P.g_hh1; bB=P.be_hh1; gH=P.g_ho1; bH=P.be_ho1;
    cs=P.c1+(size_t)row*HID; hs=P.h1+(size_t)row*HID;
    hh=P.h1h+(size_t)row*HID; hl=P.h1l+(size_t)row*HID;
  }

  for (int t = 0; t <= SEQ; ++t) {
    // ================= phase A: gate GEMMs =================
    {
      f32x4 acc[2][2][4];
      #pragma unroll
      for (int mh=0;mh<2;mh++)
        #pragma unroll
        for (int mi=0;mi<2;mi++)
          #pragma unroll
          for (int ni=0;ni<4;ni++)
            acc[mh][mi][ni] = (f32x4){0.f,0.f,0.f,0.f};

      const int tq = (t < SEQ) ? t : (SEQ-1);   // t==200 layer0 result unused

      for (int k0 = 0; k0 < Kd; k0 += 32) {
        half8 bh[4], bl[4];
        #pragma unroll
        for (int ni=0;ni<4;ni++){
          const size_t boff = (size_t)(wn0+ni*16+lrow)*Kd + k0 + lk;
          bh[ni] = *(const half8*)(Bh + boff);
          bl[ni] = *(const half8*)(Bl + boff);
        }
        #pragma unroll
        for (int mh=0;mh<2;mh++){
          half8 ah[2], al[2];
          #pragma unroll
          for (int mi=0;mi<2;mi++){
            if (which == 0) {
              const int b = wmb + mh*64 + mi*16 + lrow;
              const float m_ = P.mu[b], r_ = P.rs[b];
              const float* xp = P.x  + (size_t)b*(SEQ*DIN) + (size_t)tq*DIN + k0 + lk;
              const float* gp = P.g1 + (size_t)tq*DIN + k0 + lk;
              const float* bp = P.b1 + (size_t)tq*DIN + k0 + lk;
              #pragma unroll
              for (int j=0;j<8;j++){
                float v = (xp[j]-m_)*r_*gp[j] + bp[j];
                half_t hv = (half_t)v;
                ah[mi][j] = hv;
                al[mi][j] = (half_t)(v - (float)hv);
              }
            } else {
              const size_t aoff = (size_t)(wmb + mh*64 + mi*16 + lrow)*Kd + k0 + lk;
              ah[mi] = *(const half8*)(Ah + aoff);
              al[mi] = *(const half8*)(Al + aoff);
            }
          }
          #pragma unroll
          for (int mi=0;mi<2;mi++)
            #pragma unroll
            for (int ni=0;ni<4;ni++){
              acc[mh][mi][ni] = __builtin_amdgcn_mfma_f32_16x16x32_f16(ah[mi], bh[ni], acc[mh][mi][ni], 0,0,0);
              acc[mh][mi][ni] = __builtin_amdgcn_mfma_f32_16x16x32_f16(al[mi], bh[ni], acc[mh][mi][ni], 0,0,0);
              acc[mh][mi][ni] = __builtin_amdgcn_mfma_f32_16x16x32_f16(ah[mi], bl[ni], acc[mh][mi][ni], 0,0,0);
            }
        }
      }

      // C/D layout: col = lane&15, row = (lane>>4)*4 + r
      #pragma unroll
      for (int mh=0;mh<2;mh++){
        #pragma unroll
        for (int mi=0;mi<2;mi++){
          const int mb = wmb + mh*64 + mi*16 + (lane>>4)*4;
          #pragma unroll
          for (int ni=0;ni<4;ni++){
            const int n = wn0 + ni*16 + lrow;
            #pragma unroll
            for (int r=0;r<4;r++)
              Gout[(size_t)(mb+r)*GW + n] = acc[mh][mi][ni][r] + bnv[ni];
          }
        }
      }
    }
    grid_barrier(P.bcnt, P.bgen);

    // ================= phase B: LN + cell update =================
    {
      const bool active = (layer==0) ? (t < SEQ) : (t > 0);
      if (active) {
        float ga[32], gb[32];
        float sa=0, ssa=0, sb=0, ssb=0;
        #pragma unroll
        for (int i=0;i<32;i++){
          const int idx = ((i>>3)*512) + ((i&7)*64) + lane;  // gate=i>>3, r=i&7
          float va = Ga_[idx], vb = Gb_[idx];
          ga[i]=va; gb[i]=vb;
          sa+=va; ssa+=va*va; sb+=vb; ssb+=vb*vb;
        }
        wave_red4(sa,ssa,sb,ssb);
        const float ma = sa*(1.0f/GW);
        const float ra = rsqrtf(ssa*(1.0f/GW) - ma*ma + EPS);
        const float mb_ = sb*(1.0f/GW);
        const float rb = rsqrtf(ssb*(1.0f/GW) - mb_*mb_ + EPS);

        float u[8], so_[8];
        float su=0, suu=0, d2=0, d3=0;
        #pragma unroll
        for (int r=0;r<8;r++){
          const int j = r*64 + lane;
          float iv = ((ga[r   ]-ma)*ra*gA[j       ]+bA[j       ]) + ((gb[r   ]-mb_)*rb*gB[j       ]+bB[j       ]);
          float fv = ((ga[8+r ]-ma)*ra*gA[j+  HID ]+bA[j+  HID ]) + ((gb[8+r ]-mb_)*rb*gB[j+  HID ]+bB[j+  HID ]);
          float gv = ((ga[16+r]-ma)*ra*gA[j+2*HID ]+bA[j+2*HID ]) + ((gb[16+r]-mb_)*rb*gB[j+2*HID ]+bB[j+2*HID ]);
          float ov = ((ga[24+r]-ma)*ra*gA[j+3*HID ]+bA[j+3*HID ]) + ((gb[24+r]-mb_)*rb*gB[j+3*HID ]+bB[j+3*HID ]);
          float cn = sigf(fv)*cs[j] + sigf(iv)*tanhf(gv);
          cs[j] = cn;
          float uu = tanhf(cn);
          u[r]=uu; so_[r]=sigf(ov);
          su+=uu; suu+=uu*uu;
        }
        wave_red4(su,suu,d2,d3);
        const float mu_u = su*(1.0f/HID);
        const float ru   = rsqrtf(suu*(1.0f/HID) - mu_u*mu_u + EPS);
        #pragma unroll
        for (int r=0;r<8;r++){
          const int j = r*64 + lane;
          float v = so_[r] * ((u[r]-mu_u)*ru*gH[j] + bH[j]);
          hs[j] = v;
          half_t hv = (half_t)v;
          hh[j] = hv;
          hl[j] = (half_t)(v - (float)hv);
        }
      }
    }
    grid_barrier(P.bcnt, P.bgen);
  }
}

// ---------------- dense head ----------------
__global__ __launch_bounds__(256) void head_kernel(
    const float* __restrict__ h1,
    const float* __restrict__ Wd1, const float* __restrict__ bd1,
    const float* __restrict__ Wd2, const float* __restrict__ bd2,
    const float* __restrict__ Wd3, const float* __restrict__ bd3,
    const float* __restrict__ Wd4, const float* __restrict__ bd4,
    float* __restrict__ out)
{
  const int b = blockIdx.x;
  __shared__ float hv[HID];
  __shared__ float z1[128];
  __shared__ float z2[64];
  __shared__ float z3[32];
  const int tid = threadIdx.x;
  for (int i=tid;i<HID;i+=256) hv[i]=h1[(size_t)b*HID+i];
  __syncthreads();
  if (tid<128){
    float acc=bd1[tid]; const float* w=Wd1+(size_t)tid*512;
    for(int k=0;k<512;k++) acc+=hv[k]*w[k];
    z1[tid]=fmaxf(acc,0.f);
  }
  __syncthreads();
  if (tid<64){
    float acc=bd2[tid]; const float* w=Wd2+(size_t)tid*128;
    for(int k=0;k<128;k++) acc+=z1[k]*w[k];
    z2[tid]=fmaxf(acc,0.f);
  }
  __syncthreads();
  if (tid<32){
    float acc=bd3[tid]; const float* w=Wd3+(size_t)tid*64;
    for(int k=0;k<64;k++) acc+=z2[k]*w[k];
    z3[tid]=fmaxf(acc,0.f);
  }
  __syncthreads();
  if (tid==0){
    float acc=bd4[0];
    for(int k=0;k<32;k++) acc+=z3[k]*Wd4[k];
    out[b]=acc;
  }
}

extern "C" void kernel_launch(void* const* d_in, const int* in_sizes, int n_in,
                              void* d_out, int out_size, void* d_ws, size_t ws_size,
                              hipStream_t stream) {
  const float* x      = (const float*)d_in[0];
  const float* ln1_g  = (const float*)d_in[1];
  const float* ln1_b  = (const float*)d_in[2];
  const float* W_ih0  = (const float*)d_in[3];
  const float* b_ih0  = (const float*)d_in[4];
  const float* W_hh0  = (const float*)d_in[5];
  const float* b_hh0  = (const float*)d_in[6];
  const float* g_ih0  = (const float*)d_in[7];
  const float* be_ih0 = (const float*)d_in[8];
  const float* g_hh0  = (const float*)d_in[9];
  const float* be_hh0 = (const float*)d_in[10];
  const float* g_ho0  = (const float*)d_in[11];
  const float* be_ho0 = (const float*)d_in[12];
  const float* W_ih1  = (const float*)d_in[13];
  const float* b_ih1  = (const float*)d_in[14];
  const float* W_hh1  = (const float*)d_in[15];
  const float* b_hh1  = (const float*)d_in[16];
  const float* g_ih1  = (const float*)d_in[17];
  const float* be_ih1 = (const float*)d_in[18];
  const float* g_hh1  = (const float*)d_in[19];
  const float* be_hh1 = (const float*)d_in[20];
  const float* g_ho1  = (const float*)d_in[21];
  const float* be_ho1 = (const float*)d_in[22];
  const float* Wd1    = (const float*)d_in[23];
  const float* bd1    = (const float*)d_in[24];
  const float* Wd2    = (const float*)d_in[25];
  const float* bd2    = (const float*)d_in[26];
  const float* Wd3    = (const float*)d_in[27];
  const float* bd3    = (const float*)d_in[28];
  const float* Wd4    = (const float*)d_in[29];
  const float* bd4    = (const float*)d_in[30];
  float* out = (float*)d_out;

  // ---- workspace layout ----
  float* ws = (float*)d_ws;
  float* G  = ws;                                   // 4*512*2048 floats = 16 MB
  float* h0 = G  + 4*(size_t)BATCH*GW;              // fp32 state block (zeroed)
  float* c0 = h0 + (size_t)BATCH*HID;
  float* h1 = c0 + (size_t)BATCH*HID;
  float* c1 = h1 + (size_t)BATCH*HID;
  half_t* h0h = (half_t*)(c1 + (size_t)BATCH*HID);  // fp16 state splits (zeroed)
  half_t* h0l = h0h + (size_t)BATCH*HID;
  half_t* h1h = h0l + (size_t)BATCH*HID;
  half_t* h1l = h1h + (size_t)BATCH*HID;
  float* mu = (float*)(h1l + (size_t)BATCH*HID);    // 512
  float* rs = mu + BATCH;                           // 512
  half_t* Wh = (half_t*)(rs + BATCH);               // WTOT halves
  half_t* Wl = Wh + (size_t)WTOT;                   // WTOT halves
  int* bar = (int*)(Wl + (size_t)WTOT);             // {cnt, gen}

  hipMemsetAsync(h0, 0, 4*(size_t)BATCH*HID*4 + 4*(size_t)BATCH*HID*2, stream);
  hipMemsetAsync(bar, 0, 2*sizeof(int), stream);
  ln1_stats<<<BATCH, 256, 0, stream>>>(x, mu, rs);
  wsplit<<<(WTOT+255)/256, 256, 0, stream>>>(W_ih0, W_hh0, W_ih1, W_hh1, Wh, Wl);

  Params P;
  P.x=x; P.g1=ln1_g; P.b1=ln1_b; P.mu=mu; P.rs=rs;
  P.b_ih0=b_ih0; P.b_hh0=b_hh0; P.b_ih1=b_ih1; P.b_hh1=b_hh1;
  P.g_ih0=g_ih0; P.be_ih0=be_ih0; P.g_hh0=g_hh0; P.be_hh0=be_hh0; P.g_ho0=g_ho0; P.be_ho0=be_ho0;
  P.g_ih1=g_ih1; P.be_ih1=be_ih1; P.g_hh1=g_hh1; P.be_hh1=be_hh1; P.g_ho1=g_ho1; P.be_ho1=be_ho1;
  P.Wh=Wh; P.Wl=Wl; P.G=G;
  P.h0=h0; P.c0=c0; P.h1=h1; P.c1=c1;
  P.h0h=h0h; P.h0l=h0l; P.h1h=h1h; P.h1l=h1l;
  P.bcnt=bar; P.bgen=bar+1;

  lstm_persistent<<<NBLOCKS, 256, 0, stream>>>(P);

  head_kernel<<<BATCH, 256, 0, stream>>>(h1, Wd1, bd1, Wd2, bd2, Wd3, bd3, Wd4, bd4, out);
}